// Round 1
// baseline (208.440 us; speedup 1.0000x reference)
//
#include <hip/hip_runtime.h>
#include <hip/hip_bf16.h>

// GlobalFilter: y = irfft2(rfft2(x, ortho) * W, ortho)  over axes (1,2)
// == per-channel 14x14 circular convolution with real kernel k_c = ifft2(M_c).
//
// x: [B=128, H=14, W=14, C=768] f32
// complex_weight: [14, 8, 768, 2] f32
// y: [128, 14, 14, 768] f32
//
// k_c[p,q] = (1/196) * sum_{u=0..13} sum_{v=0..7} c_v * (Wr*cos(th) - Wi*sin(th))
//            th = 2*pi*(u*p + v*q)/14, c_v = 1 for v in {0,7}, else 2.
// (The c_v={1,...,1} endpoints implement irfft's drop-imag-at-DC/Nyquist exactly.)

#define BATCH 128
#define HH 14
#define WW 14
#define CC 768
#define SPAT 196          // 14*14
#define CPB 64            // channels per block (kernel B)
#define THREADS_B 448     // 64 channels * 7 row-groups

// ---------------- Kernel A: build per-channel spatial kernels ----------------
// grid: 196 blocks (one per output tap pq), 256 threads; each thread does 3 channels.
__global__ __launch_bounds__(256) void gf_build_k(const float* __restrict__ w,
                                                  float* __restrict__ kbuf) {
    int pq = blockIdx.x;            // 0..195
    int p = pq / 14, q = pq % 14;

    __shared__ float ct[14], st[14];
    if (threadIdx.x < 14) {
        float ang = 6.283185307179586f * (float)threadIdx.x / 14.0f;
        ct[threadIdx.x] = cosf(ang);
        st[threadIdx.x] = sinf(ang);
    }
    __syncthreads();

    for (int cc = 0; cc < 3; ++cc) {
        int c = cc * 256 + threadIdx.x;     // 0..767
        float acc = 0.f;
        #pragma unroll
        for (int u = 0; u < 14; ++u) {
            int up = (u * p) % 14;
            #pragma unroll
            for (int v = 0; v < 8; ++v) {
                int r = (up + v * q) % 14;
                float cv = (v == 0 || v == 7) ? 1.f : 2.f;
                const float* wp = w + ((size_t)(u * 8 + v) * CC + c) * 2;
                float wr = wp[0], wi = wp[1];
                acc += cv * (wr * ct[r] - wi * st[r]);
            }
        }
        kbuf[(size_t)pq * CC + c] = acc * (1.0f / 196.0f);
    }
}

// ---------------- Kernel B: depthwise circular conv ----------------
// grid: (12 channel-groups, 128 batches), 448 threads.
// LDS: xs[196][64] + ks[196][64] f32 = 100,352 B (dynamic).
// thread t: channel cl = t&63, row-group g = t>>6 (0..6) -> output rows 2g, 2g+1.
__global__ __launch_bounds__(THREADS_B, 1) void gf_conv(const float* __restrict__ x,
                                                        const float* __restrict__ kbuf,
                                                        float* __restrict__ y) {
    extern __shared__ float lds[];
    float* xs = lds;                 // [196][64]
    float* ks = lds + SPAT * CPB;    // [196][64]

    int b = blockIdx.y;
    int c0 = blockIdx.x * CPB;
    int t = threadIdx.x;

    const float* xb = x + (size_t)b * SPAT * CC + c0;
    const float* kb = kbuf + c0;

    // stage x-slice and k-slice: 12544 elements each, 28 per thread, coalesced.
    #pragma unroll
    for (int i = 0; i < 28; ++i) {
        int e = t + i * THREADS_B;   // 0..12543
        int s = e >> 6, cl = e & 63;
        xs[e] = xb[(size_t)s * CC + cl];
        ks[e] = kb[(size_t)s * CC + cl];
    }
    __syncthreads();

    int cl = t & 63;
    int g  = t >> 6;                 // 0..6
    int h0 = 2 * g;                  // output rows h0, h0+1

    float y0[14], y1[14];
    #pragma unroll
    for (int w = 0; w < 14; ++w) { y0[w] = 0.f; y1[w] = 0.f; }

    for (int r = 0; r < 14; ++r) {   // input row
        float xr[14];
        #pragma unroll
        for (int w = 0; w < 14; ++w)
            xr[w] = xs[(r * 14 + w) * CPB + cl];

        int p0 = h0 - r;  if (p0 < 0) p0 += 14;       // k-row for output row h0
        int p1 = p0 + 1;  if (p1 >= 14) p1 -= 14;     // k-row for output row h0+1

        #pragma unroll
        for (int q = 0; q < 14; ++q) {
            float k0 = ks[(p0 * 14 + q) * CPB + cl];
            float k1 = ks[(p1 * 14 + q) * CPB + cl];
            #pragma unroll
            for (int w = 0; w < 14; ++w) {
                float xv = xr[(w - q + 14) % 14];
                y0[w] += k0 * xv;
                y1[w] += k1 * xv;
            }
        }
    }

    float* yb = y + (size_t)b * SPAT * CC + c0;
    #pragma unroll
    for (int w = 0; w < 14; ++w) {
        yb[(size_t)((h0)     * 14 + w) * CC + cl] = y0[w];
        yb[(size_t)((h0 + 1) * 14 + w) * CC + cl] = y1[w];
    }
}

extern "C" void kernel_launch(void* const* d_in, const int* in_sizes, int n_in,
                              void* d_out, int out_size, void* d_ws, size_t ws_size,
                              hipStream_t stream) {
    const float* x = (const float*)d_in[0];
    const float* w = (const float*)d_in[1];
    float* y = (float*)d_out;
    float* kbuf = (float*)d_ws;      // 196*768*4 = 602,112 B

    // Kernel A: build spatial kernels
    gf_build_k<<<dim3(SPAT), dim3(256), 0, stream>>>(w, kbuf);

    // Kernel B: depthwise circular conv
    dim3 grid(CC / CPB, BATCH);      // (12, 128)
    size_t lds_bytes = 2 * SPAT * CPB * sizeof(float);   // 100,352 B
    gf_conv<<<grid, dim3(THREADS_B), lds_bytes, stream>>>(x, kbuf, y);
}

// Round 2
// 104.438 us; speedup vs baseline: 1.9958x; 1.9958x over previous
//
#include <hip/hip_runtime.h>
#include <hip/hip_bf16.h>

// GlobalFilter: y = irfft2(rfft2(x, ortho) * W, ortho) over axes (1,2)
// == per-channel 14x14 circular convolution with real kernel k_c = ifft2(M_c):
//   k_c[p,q] = (1/196) * sum_{u<14, v<8} c_v * (Wr*cos(th) - Wi*sin(th)),
//   th = 2*pi*(u*p + v*q)/14, c_v = 1 for v in {0,7} else 2.
//
// v2: f16 dot2 path. Kernel rows packed in h-pairs:
//   kd[m][q] = half2(k[2m][q], k[(2m-1)%14][q])     m=0..6
//   xe[i][w] = half2(x[2i][w], x[2i+1][w])          i=0..6
//   xo[i][w] = half2(x[2i+1][w], x[(2i+2)%14][w])
// Output rows (2g, 2g+1) both use kd[(g-i)%7] against xe[i]/xo[i]:
//   y0[w] += dot2(kd[m][q], xe[i][(w-q)%14]);  y1[w] += dot2(kd[m][q], xo[i][(w-q)%14])

typedef _Float16 h2 __attribute__((ext_vector_type(2)));

#define BATCH 128
#define CC 768
#define SPAT 196
#define CPB 64
#define TB 448

// ---------------- Kernel A: build packed spatial kernels kd[7][14][768] (u32=half2) ----
// grid (12 ch-groups, 7 m), 896 threads = 14 q x 64 ch. W slice staged in LDS once.
__global__ __launch_bounds__(896) void gf_build_kd(const float* __restrict__ wg,
                                                   unsigned int* __restrict__ kd) {
    __shared__ float ws[112 * 128];        // [uv][cl][ri], pre-scaled by cv/196
    __shared__ float ct[14], st[14];
    int t = threadIdx.x;
    int c0 = blockIdx.x * 64;
    int m  = blockIdx.y;
    if (t < 14) {
        float ang = 6.283185307179586f * (float)t / 14.0f;
        ct[t] = cosf(ang);
        st[t] = sinf(ang);
    }
    #pragma unroll
    for (int j = 0; j < 16; ++j) {
        int f = t + j * 896;               // 0..14335
        int uv = f >> 7;
        int v = uv & 7;
        float scale = (v == 0 || v == 7) ? (1.0f / 196.0f) : (2.0f / 196.0f);
        ws[f] = wg[(size_t)uv * 1536 + (size_t)c0 * 2 + (f & 127)] * scale;
    }
    __syncthreads();

    int q = t >> 6, cl = t & 63;
    int pe = 2 * m;                        // even tap row
    int po = (pe + 13) % 14;               // (2m-1) mod 14
    float ae = 0.f, ao = 0.f;
    int upe = 0, upo = 0;                  // (u*p) % 14, running
    #pragma unroll
    for (int u = 0; u < 14; ++u) {
        int vq = 0;                        // (v*q) % 14, running
        #pragma unroll
        for (int v = 0; v < 8; ++v) {
            int re = upe + vq; if (re >= 14) re -= 14;
            int ro = upo + vq; if (ro >= 14) ro -= 14;
            float wr = ws[(u * 8 + v) * 128 + cl * 2];
            float wi = ws[(u * 8 + v) * 128 + cl * 2 + 1];
            ae += wr * ct[re]; ae -= wi * st[re];
            ao += wr * ct[ro]; ao -= wi * st[ro];
            vq += q; if (vq >= 14) vq -= 14;
        }
        upe += pe; if (upe >= 14) upe -= 14;
        upo += po; if (upo >= 14) upo -= 14;
    }
    h2 pk; pk.x = (_Float16)ae; pk.y = (_Float16)ao;
    kd[((size_t)m * 14 + q) * CC + c0 + cl] = __builtin_bit_cast(unsigned int, pk);
}

// ---------------- Kernel B: depthwise circular conv, dot2 path ----------------
// grid (12, 128), 448 threads. LDS: xe[6272] + xo[6272] + kd[6272] u32 = 75,264 B
// -> 2 blocks/CU. thread t: channel cl=t&63, g=t>>6 -> output rows 2g, 2g+1.
__global__ __launch_bounds__(TB) void gf_conv(const float* __restrict__ x,
                                              const unsigned int* __restrict__ kd,
                                              float* __restrict__ y) {
    extern __shared__ unsigned int lds[];  // xe @0, xo @6272, kd @12544
    int b = blockIdx.y;
    int c0 = blockIdx.x * CPB;
    int t = threadIdx.x;
    const float* xb = x + (size_t)b * SPAT * CC + c0;

    // stage kd slice: [98][64] u32, coalesced
    #pragma unroll
    for (int j = 0; j < 14; ++j) {
        int e = t + j * TB;                // 0..6271
        lds[12544 + e] = kd[(size_t)(e >> 6) * CC + c0 + (e & 63)];
    }
    // stage xe/xo: convert f32 -> half2 row-pairs
    #pragma unroll
    for (int j = 0; j < 14; ++j) {
        int e = t + j * TB;                // 0..6271
        int i = e / 896;                   // const-divisor -> magic mul
        int rem = e - i * 896;             // w*64 + cl
        int w_ = rem >> 6, cl_ = rem & 63;
        int r0 = 2 * i, r1 = 2 * i + 1;
        int r2 = (r1 + 1 == 14) ? 0 : r1 + 1;
        float a  = xb[((size_t)r0 * 14 + w_) * CC + cl_];
        float bb = xb[((size_t)r1 * 14 + w_) * CC + cl_];
        float c2 = xb[((size_t)r2 * 14 + w_) * CC + cl_];
        h2 pe_; pe_.x = (_Float16)a;  pe_.y = (_Float16)bb;
        h2 po_; po_.x = (_Float16)bb; po_.y = (_Float16)c2;
        lds[e]        = __builtin_bit_cast(unsigned int, pe_);
        lds[6272 + e] = __builtin_bit_cast(unsigned int, po_);
    }
    __syncthreads();

    int cl = t & 63, g = t >> 6;
    float y0[14], y1[14];
    #pragma unroll
    for (int w = 0; w < 14; ++w) { y0[w] = 0.f; y1[w] = 0.f; }

    int m = g;
    #pragma unroll
    for (int i = 0; i < 7; ++i) {
        h2 xev[14], xov[14];
        #pragma unroll
        for (int w = 0; w < 14; ++w) {
            xev[w] = __builtin_bit_cast(h2, lds[i * 896 + w * 64 + cl]);
            xov[w] = __builtin_bit_cast(h2, lds[6272 + i * 896 + w * 64 + cl]);
        }
        #pragma unroll
        for (int q = 0; q < 14; ++q) {
            h2 kq = __builtin_bit_cast(h2, lds[12544 + m * 896 + q * 64 + cl]);
            #pragma unroll
            for (int w = 0; w < 14; ++w) {
                int src = w - q; if (src < 0) src += 14;   // compile-time after unroll
                y0[w] = __builtin_amdgcn_fdot2(kq, xev[src], y0[w], false);
                y1[w] = __builtin_amdgcn_fdot2(kq, xov[src], y1[w], false);
            }
        }
        m = (m == 0) ? 6 : m - 1;          // m = (g - i) mod 7
    }

    float* yb = y + (size_t)b * SPAT * CC + c0;
    int h0 = 2 * g;
    #pragma unroll
    for (int w = 0; w < 14; ++w) {
        yb[((size_t)h0 * 14 + w) * CC + cl]       = y0[w];
        yb[((size_t)(h0 + 1) * 14 + w) * CC + cl] = y1[w];
    }
}

extern "C" void kernel_launch(void* const* d_in, const int* in_sizes, int n_in,
                              void* d_out, int out_size, void* d_ws, size_t ws_size,
                              hipStream_t stream) {
    const float* x = (const float*)d_in[0];
    const float* w = (const float*)d_in[1];
    float* y = (float*)d_out;
    unsigned int* kbuf = (unsigned int*)d_ws;   // 98*768*4 = 301,056 B

    gf_build_kd<<<dim3(12, 7), dim3(896), 0, stream>>>(w, kbuf);

    dim3 grid(CC / CPB, BATCH);                 // (12, 128)
    size_t lds_bytes = 3 * 6272 * sizeof(unsigned int);   // 75,264 B
    gf_conv<<<grid, dim3(TB), lds_bytes, stream>>>(x, kbuf, y);
}